// Round 4
// baseline (406.219 us; speedup 1.0000x reference)
//
#include <hip/hip_runtime.h>
#include <hip/hip_bf16.h>
#include <cstdint>
#include <cstddef>

// ---------------------------------------------------------------------------
// GAT 2-layer forward. N=50000, E=800000 (+N self loops), H=8 heads.
// Layer1: Fin=128 -> 8x32 (=256), lrelu(0.2). Layer2: 256 -> 8x4 (=32).
// R3: (a) segment-softmax max pass eliminated (exp without max subtraction;
// alphas are O(1) dots, denominator cancellation is exact); (b) aggregation
// pass spreads asrc gather + exp across all 64 lanes (one (edge,head) per
// lane per 8-edge chunk); (c) agg blocks shrunk to 128 threads (2 waves) for
// load balance across degree variance.
// ---------------------------------------------------------------------------

__device__ __forceinline__ float lrelu(float a) { return a > 0.f ? a : 0.2f * a; }

__device__ __forceinline__ unsigned short f2bf(float f) {
  unsigned u = __float_as_uint(f);
  unsigned r = (u + 0x7fff + ((u >> 16) & 1)) >> 16;  // RNE
  return (unsigned short)r;
}
__device__ __forceinline__ float bf_lo(unsigned q) { return __uint_as_float(q << 16); }
__device__ __forceinline__ float bf_hi(unsigned q) { return __uint_as_float(q & 0xffff0000u); }

// -------------------- CSR build --------------------

__global__ __launch_bounds__(256) void k_hist(const int* __restrict__ dste, int E, int n,
                                              int* __restrict__ cnt) {
  int t = blockIdx.x * 256 + threadIdx.x;
  if (t >= E + n) return;
  int d = (t < E) ? dste[t] : (t - E);   // self-loop for node t-E
  atomicAdd(&cnt[d], 1);
}

__global__ __launch_bounds__(256) void k_scan1(const int* __restrict__ cnt, int n,
                                               int* __restrict__ bsum) {
  __shared__ int sb[256];
  int i0 = blockIdx.x * 1024 + threadIdx.x * 4;
  int s = 0;
#pragma unroll
  for (int j = 0; j < 4; j++) { int i = i0 + j; if (i < n) s += cnt[i]; }
  sb[threadIdx.x] = s;
  __syncthreads();
  for (int off = 128; off > 0; off >>= 1) {
    if (threadIdx.x < off) sb[threadIdx.x] += sb[threadIdx.x + off];
    __syncthreads();
  }
  if (threadIdx.x == 0) bsum[blockIdx.x] = sb[0];
}

__global__ void k_scan2(const int* __restrict__ bsum, int nb, int* __restrict__ boff,
                        int* __restrict__ row_ptr, int n) {
  if (threadIdx.x == 0 && blockIdx.x == 0) {
    int run = 0;
    for (int j = 0; j < nb; j++) { boff[j] = run; run += bsum[j]; }
    row_ptr[n] = run;
  }
}

__global__ __launch_bounds__(256) void k_scan3(const int* __restrict__ cnt,
                                               const int* __restrict__ boff, int n,
                                               int* __restrict__ row_ptr,
                                               int* __restrict__ cursor) {
  __shared__ int sb[256];
  int i0 = blockIdx.x * 1024 + threadIdx.x * 4;
  int c[4];
  int s = 0;
#pragma unroll
  for (int j = 0; j < 4; j++) { int i = i0 + j; c[j] = (i < n) ? cnt[i] : 0; s += c[j]; }
  sb[threadIdx.x] = s;
  __syncthreads();
  for (int off = 1; off < 256; off <<= 1) {
    int add = (threadIdx.x >= off) ? sb[threadIdx.x - off] : 0;
    __syncthreads();
    sb[threadIdx.x] += add;
    __syncthreads();
  }
  int excl = sb[threadIdx.x] - s + boff[blockIdx.x];
#pragma unroll
  for (int j = 0; j < 4; j++) {
    int i = i0 + j;
    if (i < n) { row_ptr[i] = excl; cursor[i] = excl; excl += c[j]; }
  }
}

__global__ __launch_bounds__(256) void k_scatter(const int* __restrict__ srce,
                                                 const int* __restrict__ dste, int E, int n,
                                                 int* __restrict__ cursor,
                                                 int* __restrict__ srcs) {
  int t = blockIdx.x * 256 + threadIdx.x;
  if (t >= E + n) return;
  int s, d;
  if (t < E) { s = srce[t]; d = dste[t]; } else { s = d = t - E; }
  int pos = atomicAdd(&cursor[d], 1);
  srcs[pos] = s;
}

// -------------------- GEMM1 + alpha epilogue --------------------

// X[M,128] @ W[128,256] -> h1 (bf16, [M,256]) + a_s1/a_d1 ([M,8], fp32).
__global__ __launch_bounds__(256) void gemm1(const float* __restrict__ X,
                                             const float* __restrict__ W,
                                             const float* __restrict__ a_src,
                                             const float* __restrict__ a_dst,
                                             unsigned short* __restrict__ h1,
                                             float* __restrict__ a_s1,
                                             float* __restrict__ a_d1, int M) {
  __shared__ float lx[64 * 128];  // 32 KB
  int row0 = blockIdx.x * 64;
#pragma unroll
  for (int i = 0; i < 8; i++) {
    int j = threadIdx.x + 256 * i;   // float4 index, 2048 total
    int r = j >> 5;                  // row within tile
    float4 v = make_float4(0.f, 0.f, 0.f, 0.f);
    if (row0 + r < M) v = *(const float4*)&X[(size_t)row0 * 128 + (size_t)j * 4];
    *(float4*)&lx[j * 4] = v;
  }
  __syncthreads();
  int tc = threadIdx.x & 63;   // col group: cols 4*tc..4*tc+3  (== lane)
  int tr = threadIdx.x >> 6;   // row group: rows tr*16..tr*16+15
  const float* lrow = &lx[tr * 16 * 128];
  float4 acc[16];
#pragma unroll
  for (int i = 0; i < 16; i++) acc[i] = make_float4(0.f, 0.f, 0.f, 0.f);
  for (int k4 = 0; k4 < 128; k4 += 4) {
    float4 w0 = *(const float4*)&W[(k4 + 0) * 256 + tc * 4];
    float4 w1 = *(const float4*)&W[(k4 + 1) * 256 + tc * 4];
    float4 w2 = *(const float4*)&W[(k4 + 2) * 256 + tc * 4];
    float4 w3 = *(const float4*)&W[(k4 + 3) * 256 + tc * 4];
#pragma unroll
    for (int i = 0; i < 16; i++) {
      float4 xv = *(const float4*)&lrow[i * 128 + k4];  // wave-uniform b128 broadcast
      acc[i].x = fmaf(xv.x, w0.x, acc[i].x);
      acc[i].y = fmaf(xv.x, w0.y, acc[i].y);
      acc[i].z = fmaf(xv.x, w0.z, acc[i].z);
      acc[i].w = fmaf(xv.x, w0.w, acc[i].w);
      acc[i].x = fmaf(xv.y, w1.x, acc[i].x);
      acc[i].y = fmaf(xv.y, w1.y, acc[i].y);
      acc[i].z = fmaf(xv.y, w1.z, acc[i].z);
      acc[i].w = fmaf(xv.y, w1.w, acc[i].w);
      acc[i].x = fmaf(xv.z, w2.x, acc[i].x);
      acc[i].y = fmaf(xv.z, w2.y, acc[i].y);
      acc[i].z = fmaf(xv.z, w2.z, acc[i].z);
      acc[i].w = fmaf(xv.z, w2.w, acc[i].w);
      acc[i].x = fmaf(xv.w, w3.x, acc[i].x);
      acc[i].y = fmaf(xv.w, w3.y, acc[i].y);
      acc[i].z = fmaf(xv.w, w3.z, acc[i].z);
      acc[i].w = fmaf(xv.w, w3.w, acc[i].w);
    }
  }
  // epilogue: bf16 store + per-head alpha dots (fp32 accumulators).
  int hh = tc >> 3;            // head 0..7
  int c0 = (tc & 7) * 4;       // channel offset within head
  float4 asv = *(const float4*)&a_src[hh * 32 + c0];
  float4 adv = *(const float4*)&a_dst[hh * 32 + c0];
  bool writer = (tc & 7) == 0;
#pragma unroll
  for (int i = 0; i < 16; i++) {
    int r = row0 + tr * 16 + i;
    float ps = acc[i].x * asv.x;
    ps = fmaf(acc[i].y, asv.y, ps);
    ps = fmaf(acc[i].z, asv.z, ps);
    ps = fmaf(acc[i].w, asv.w, ps);
    float pd = acc[i].x * adv.x;
    pd = fmaf(acc[i].y, adv.y, pd);
    pd = fmaf(acc[i].z, adv.z, pd);
    pd = fmaf(acc[i].w, adv.w, pd);
    ps += __shfl_xor(ps, 1); ps += __shfl_xor(ps, 2); ps += __shfl_xor(ps, 4);
    pd += __shfl_xor(pd, 1); pd += __shfl_xor(pd, 2); pd += __shfl_xor(pd, 4);
    if (r < M) {
      uint2 p;
      p.x = (unsigned)f2bf(acc[i].x) | ((unsigned)f2bf(acc[i].y) << 16);
      p.y = (unsigned)f2bf(acc[i].z) | ((unsigned)f2bf(acc[i].w) << 16);
      *(uint2*)&h1[(size_t)r * 256 + tc * 4] = p;
      if (writer) { a_s1[r * 8 + hh] = ps; a_d1[r * 8 + hh] = pd; }
    }
  }
}

// -------------------- GEMM2 + alpha epilogue --------------------

__global__ __launch_bounds__(256) void gemm2(const float* __restrict__ X,
                                             const float* __restrict__ W,
                                             const float* __restrict__ a_src,
                                             const float* __restrict__ a_dst,
                                             float* __restrict__ h2,
                                             float* __restrict__ a_s2,
                                             float* __restrict__ a_d2, int M) {
  __shared__ float lx[64 * 132];  // padded stride 132
  int row0 = blockIdx.x * 64;
  int tc = threadIdx.x & 7;    // head; cols 4*tc..4*tc+3
  int tr = threadIdx.x >> 3;   // rows tr*2, tr*2+1
  float4 acc[2];
  acc[0] = make_float4(0.f, 0.f, 0.f, 0.f);
  acc[1] = make_float4(0.f, 0.f, 0.f, 0.f);
  for (int kk = 0; kk < 256; kk += 128) {
    __syncthreads();
#pragma unroll
    for (int i = 0; i < 8; i++) {
      int j = threadIdx.x + 256 * i;  // float4 index, 2048 total
      int r = j >> 5;
      int c = (j & 31) * 4;
      float4 v = make_float4(0.f, 0.f, 0.f, 0.f);
      if (row0 + r < M) v = *(const float4*)&X[(size_t)(row0 + r) * 256 + kk + c];
      *(float4*)&lx[r * 132 + c] = v;
    }
    __syncthreads();
    for (int k = 0; k < 128; k++) {
      float4 w4 = *(const float4*)&W[(kk + k) * 32 + tc * 4];
#pragma unroll
      for (int i = 0; i < 2; i++) {
        float xv = lx[(tr * 2 + i) * 132 + k];
        acc[i].x = fmaf(xv, w4.x, acc[i].x);
        acc[i].y = fmaf(xv, w4.y, acc[i].y);
        acc[i].z = fmaf(xv, w4.z, acc[i].z);
        acc[i].w = fmaf(xv, w4.w, acc[i].w);
      }
    }
  }
  float4 asv = *(const float4*)&a_src[tc * 4];
  float4 adv = *(const float4*)&a_dst[tc * 4];
#pragma unroll
  for (int i = 0; i < 2; i++) {
    int r = row0 + tr * 2 + i;
    if (r < M) {
      float ps = acc[i].x * asv.x;
      ps = fmaf(acc[i].y, asv.y, ps);
      ps = fmaf(acc[i].z, asv.z, ps);
      ps = fmaf(acc[i].w, asv.w, ps);
      float pd = acc[i].x * adv.x;
      pd = fmaf(acc[i].y, adv.y, pd);
      pd = fmaf(acc[i].z, adv.z, pd);
      pd = fmaf(acc[i].w, adv.w, pd);
      *(float4*)&h2[(size_t)r * 32 + tc * 4] = acc[i];
      a_s2[r * 8 + tc] = ps;
      a_d2[r * 8 + tc] = pd;
    }
  }
}

// -------------------- segment softmax + aggregation --------------------

// Layer 1: F=256 bf16. One wave per dst; lane owns 4 bf16 (8 B) at channel
// lane*4, head eg = lane>>3. Single pass (no max subtraction). Per 8-edge
// chunk: each lane gathers one (edge,head) logit + exp; srcs go through the
// scalar path for the h-gather addresses; per-head weights broadcast by shfl.
__global__ __launch_bounds__(128) void gat_agg_l1(const unsigned short* __restrict__ h,
                                                  const float* __restrict__ asrc,
                                                  const float* __restrict__ adst,
                                                  const int* __restrict__ row_ptr,
                                                  const int* __restrict__ srcs,
                                                  const float* __restrict__ bias,
                                                  float* __restrict__ out, int n) {
  int wave = threadIdx.x >> 6;
  int lane = threadIdx.x & 63;
  int d = blockIdx.x * 2 + wave;
  if (d >= n) return;
  int begin = row_ptr[d];
  int end = row_ptr[d + 1];
  int hh = lane & 7;
  int eg = lane >> 3;          // == head this lane accumulates (channels lane*4..+3)
  float ad = adst[d * 8 + hh];

  float denom = 0.f;
  float4 acc = make_float4(0.f, 0.f, 0.f, 0.f);
  for (int base = begin; base < end; base += 8) {
    int e = base + eg;
    float w = 0.f;
    if (e < end) {
      int sv = srcs[e];
      w = __expf(lrelu(asrc[sv * 8 + hh] + ad));
    }
    denom += w;
#pragma unroll
    for (int j = 0; j < 8; j++) {
      if (base + j < end) {                       // wave-uniform condition
        int sj = srcs[base + j];                  // scalar-path load
        float wj = __shfl(w, j * 8 + eg);         // weight for (edge j, head eg)
        uint2 q = *(const uint2*)&h[(size_t)sj * 256 + lane * 4];
        acc.x = fmaf(wj, bf_lo(q.x), acc.x);
        acc.y = fmaf(wj, bf_hi(q.x), acc.y);
        acc.z = fmaf(wj, bf_lo(q.y), acc.z);
        acc.w = fmaf(wj, bf_hi(q.y), acc.w);
      }
    }
  }
  // denom currently per (eg,hh); sum over eg so each lane has total for head hh.
  denom += __shfl_xor(denom, 8);
  denom += __shfl_xor(denom, 16);
  denom += __shfl_xor(denom, 32);
  float dn = __shfl(denom, eg) + 1e-16f;  // lane 'eg' (<8) holds head eg's denom
  float inv = 1.f / dn;
  int f = lane * 4;
  float4 bv = *(const float4*)&bias[f];
  float4 r;
  r.x = lrelu(acc.x * inv + bv.x);
  r.y = lrelu(acc.y * inv + bv.y);
  r.z = lrelu(acc.z * inv + bv.z);
  r.w = lrelu(acc.w * inv + bv.w);
  *(float4*)&out[(size_t)d * 256 + f] = r;
}

// Layer 2: C=4, F=32. One wave per dst; 8 edges in parallel
// (lane = edge-group*8 + head). Single pass, no max subtraction.
__global__ __launch_bounds__(128) void gat_agg_l2(const float* __restrict__ h,
                                                  const float* __restrict__ asrc,
                                                  const float* __restrict__ adst,
                                                  const int* __restrict__ row_ptr,
                                                  const int* __restrict__ srcs,
                                                  const float* __restrict__ bias,
                                                  float* __restrict__ out, int n) {
  int wave = threadIdx.x >> 6;
  int lane = threadIdx.x & 63;
  int d = blockIdx.x * 2 + wave;
  if (d >= n) return;
  int begin = row_ptr[d];
  int end = row_ptr[d + 1];
  int hh = lane & 7;
  int eg = lane >> 3;
  float ad = adst[d * 8 + hh];

  float denom = 0.f;
  float4 acc = make_float4(0.f, 0.f, 0.f, 0.f);
  for (int base = begin; base < end; base += 8) {
    int e = base + eg;
    if (e < end) {
      int s = srcs[e];
      float w = __expf(lrelu(asrc[s * 8 + hh] + ad));
      denom += w;
      const float4 hv = *(const float4*)&h[(size_t)s * 32 + hh * 4];
      acc.x = fmaf(w, hv.x, acc.x);
      acc.y = fmaf(w, hv.y, acc.y);
      acc.z = fmaf(w, hv.z, acc.z);
      acc.w = fmaf(w, hv.w, acc.w);
    }
  }
#pragma unroll
  for (int mask = 8; mask <= 32; mask <<= 1) {
    denom += __shfl_xor(denom, mask);
    acc.x += __shfl_xor(acc.x, mask);
    acc.y += __shfl_xor(acc.y, mask);
    acc.z += __shfl_xor(acc.z, mask);
    acc.w += __shfl_xor(acc.w, mask);
  }
  if (lane < 8) {
    float inv = 1.f / (denom + 1e-16f);
    int f = lane * 4;
    float4 bv = *(const float4*)&bias[f];
    float4 r;
    r.x = acc.x * inv + bv.x;
    r.y = acc.y * inv + bv.y;
    r.z = acc.z * inv + bv.z;
    r.w = acc.w * inv + bv.w;
    *(float4*)&out[(size_t)d * 32 + f] = r;
  }
}

// -------------------- launcher --------------------

extern "C" void kernel_launch(void* const* d_in, const int* in_sizes, int n_in,
                              void* d_out, int out_size, void* d_ws, size_t ws_size,
                              hipStream_t stream) {
  const float* x   = (const float*)d_in[0];
  const int*   ei  = (const int*)d_in[1];
  const float* W1  = (const float*)d_in[2];
  const float* as1 = (const float*)d_in[3];
  const float* ad1 = (const float*)d_in[4];
  const float* b1  = (const float*)d_in[5];
  const float* W2  = (const float*)d_in[6];
  const float* as2 = (const float*)d_in[7];
  const float* ad2 = (const float*)d_in[8];
  const float* b2  = (const float*)d_in[9];
  float* out = (float*)d_out;

  const int E = in_sizes[1] / 2;
  const int n = in_sizes[0] / 128;
  const int* srce = ei;
  const int* dste = ei + E;

  char* ws = (char*)d_ws;
  size_t off = 0;
  auto alloc = [&](size_t bytes) -> void* {
    void* p = ws + off;
    off = (off + bytes + 255) & ~(size_t)255;
    return p;
  };
  int* cnt      = (int*)alloc((size_t)n * 4);
  int* row_ptr  = (int*)alloc((size_t)(n + 1) * 4);
  int* cursor   = (int*)alloc((size_t)n * 4);
  int* bsum     = (int*)alloc(256 * 4);
  int* boff     = (int*)alloc(256 * 4);
  int* srcs     = (int*)alloc((size_t)(E + n) * 4);
  unsigned short* h1 = (unsigned short*)alloc((size_t)n * 256 * 2);  // bf16
  float* a_s1   = (float*)alloc((size_t)n * 8 * 4);
  float* a_d1   = (float*)alloc((size_t)n * 8 * 4);
  float* x2     = (float*)alloc((size_t)n * 256 * 4);
  float* h2     = (float*)alloc((size_t)n * 32 * 4);
  float* a_s2   = (float*)alloc((size_t)n * 8 * 4);
  float* a_d2   = (float*)alloc((size_t)n * 8 * 4);

  const int tot = E + n;
  hipMemsetAsync(cnt, 0, (size_t)n * 4, stream);
  k_hist<<<(tot + 255) / 256, 256, 0, stream>>>(dste, E, n, cnt);
  const int nb = (n + 1023) / 1024;
  k_scan1<<<nb, 256, 0, stream>>>(cnt, n, bsum);
  k_scan2<<<1, 64, 0, stream>>>(bsum, nb, boff, row_ptr, n);
  k_scan3<<<nb, 256, 0, stream>>>(cnt, boff, n, row_ptr, cursor);
  k_scatter<<<(tot + 255) / 256, 256, 0, stream>>>(srce, dste, E, n, cursor, srcs);

  gemm1<<<(n + 63) / 64, 256, 0, stream>>>(x, W1, as1, ad1, h1, a_s1, a_d1, n);
  gat_agg_l1<<<(n + 1) / 2, 128, 0, stream>>>(h1, a_s1, a_d1, row_ptr, srcs, b1, x2, n);

  gemm2<<<(n + 63) / 64, 256, 0, stream>>>(x2, W2, as2, ad2, h2, a_s2, a_d2, n);
  gat_agg_l2<<<(n + 1) / 2, 128, 0, stream>>>(h2, a_s2, a_d2, row_ptr, srcs, b2, out, n);
}

// Round 5
// 384.249 us; speedup vs baseline: 1.0572x; 1.0572x over previous
//
#include <hip/hip_runtime.h>
#include <hip/hip_bf16.h>
#include <cstdint>
#include <cstddef>

// ---------------------------------------------------------------------------
// GAT 2-layer forward. N=50000, E=800000 (+N self loops), H=8 heads.
// Layer1: Fin=128 -> 8x32 (=256), lrelu(0.2). Layer2: 256 -> 8x4 (=32).
// R4: revert aggregation to the R2 batched-load structure (8 independent
// h-gathers issued upfront per chunk -> 8 loads in flight; R3's interleaved
// loop collapsed MLP, VALUBusy 48->23%), keeping the validated single-pass
// softmax (no max subtraction; exact denominator cancellation, absmax
// unchanged). 256-thread blocks restored.
// ---------------------------------------------------------------------------

__device__ __forceinline__ float lrelu(float a) { return a > 0.f ? a : 0.2f * a; }

__device__ __forceinline__ unsigned short f2bf(float f) {
  unsigned u = __float_as_uint(f);
  unsigned r = (u + 0x7fff + ((u >> 16) & 1)) >> 16;  // RNE
  return (unsigned short)r;
}
__device__ __forceinline__ float bf_lo(unsigned q) { return __uint_as_float(q << 16); }
__device__ __forceinline__ float bf_hi(unsigned q) { return __uint_as_float(q & 0xffff0000u); }

// -------------------- CSR build --------------------

__global__ __launch_bounds__(256) void k_hist(const int* __restrict__ dste, int E, int n,
                                              int* __restrict__ cnt) {
  int t = blockIdx.x * 256 + threadIdx.x;
  if (t >= E + n) return;
  int d = (t < E) ? dste[t] : (t - E);   // self-loop for node t-E
  atomicAdd(&cnt[d], 1);
}

__global__ __launch_bounds__(256) void k_scan1(const int* __restrict__ cnt, int n,
                                               int* __restrict__ bsum) {
  __shared__ int sb[256];
  int i0 = blockIdx.x * 1024 + threadIdx.x * 4;
  int s = 0;
#pragma unroll
  for (int j = 0; j < 4; j++) { int i = i0 + j; if (i < n) s += cnt[i]; }
  sb[threadIdx.x] = s;
  __syncthreads();
  for (int off = 128; off > 0; off >>= 1) {
    if (threadIdx.x < off) sb[threadIdx.x] += sb[threadIdx.x + off];
    __syncthreads();
  }
  if (threadIdx.x == 0) bsum[blockIdx.x] = sb[0];
}

__global__ void k_scan2(const int* __restrict__ bsum, int nb, int* __restrict__ boff,
                        int* __restrict__ row_ptr, int n) {
  if (threadIdx.x == 0 && blockIdx.x == 0) {
    int run = 0;
    for (int j = 0; j < nb; j++) { boff[j] = run; run += bsum[j]; }
    row_ptr[n] = run;
  }
}

__global__ __launch_bounds__(256) void k_scan3(const int* __restrict__ cnt,
                                               const int* __restrict__ boff, int n,
                                               int* __restrict__ row_ptr,
                                               int* __restrict__ cursor) {
  __shared__ int sb[256];
  int i0 = blockIdx.x * 1024 + threadIdx.x * 4;
  int c[4];
  int s = 0;
#pragma unroll
  for (int j = 0; j < 4; j++) { int i = i0 + j; c[j] = (i < n) ? cnt[i] : 0; s += c[j]; }
  sb[threadIdx.x] = s;
  __syncthreads();
  for (int off = 1; off < 256; off <<= 1) {
    int add = (threadIdx.x >= off) ? sb[threadIdx.x - off] : 0;
    __syncthreads();
    sb[threadIdx.x] += add;
    __syncthreads();
  }
  int excl = sb[threadIdx.x] - s + boff[blockIdx.x];
#pragma unroll
  for (int j = 0; j < 4; j++) {
    int i = i0 + j;
    if (i < n) { row_ptr[i] = excl; cursor[i] = excl; excl += c[j]; }
  }
}

__global__ __launch_bounds__(256) void k_scatter(const int* __restrict__ srce,
                                                 const int* __restrict__ dste, int E, int n,
                                                 int* __restrict__ cursor,
                                                 int* __restrict__ srcs) {
  int t = blockIdx.x * 256 + threadIdx.x;
  if (t >= E + n) return;
  int s, d;
  if (t < E) { s = srce[t]; d = dste[t]; } else { s = d = t - E; }
  int pos = atomicAdd(&cursor[d], 1);
  srcs[pos] = s;
}

// -------------------- GEMM1 + alpha epilogue --------------------

// X[M,128] @ W[128,256] -> h1 (bf16, [M,256]) + a_s1/a_d1 ([M,8], fp32).
__global__ __launch_bounds__(256) void gemm1(const float* __restrict__ X,
                                             const float* __restrict__ W,
                                             const float* __restrict__ a_src,
                                             const float* __restrict__ a_dst,
                                             unsigned short* __restrict__ h1,
                                             float* __restrict__ a_s1,
                                             float* __restrict__ a_d1, int M) {
  __shared__ float lx[64 * 128];  // 32 KB
  int row0 = blockIdx.x * 64;
#pragma unroll
  for (int i = 0; i < 8; i++) {
    int j = threadIdx.x + 256 * i;   // float4 index, 2048 total
    int r = j >> 5;                  // row within tile
    float4 v = make_float4(0.f, 0.f, 0.f, 0.f);
    if (row0 + r < M) v = *(const float4*)&X[(size_t)row0 * 128 + (size_t)j * 4];
    *(float4*)&lx[j * 4] = v;
  }
  __syncthreads();
  int tc = threadIdx.x & 63;   // col group: cols 4*tc..4*tc+3  (== lane)
  int tr = threadIdx.x >> 6;   // row group: rows tr*16..tr*16+15
  const float* lrow = &lx[tr * 16 * 128];
  float4 acc[16];
#pragma unroll
  for (int i = 0; i < 16; i++) acc[i] = make_float4(0.f, 0.f, 0.f, 0.f);
  for (int k4 = 0; k4 < 128; k4 += 4) {
    float4 w0 = *(const float4*)&W[(k4 + 0) * 256 + tc * 4];
    float4 w1 = *(const float4*)&W[(k4 + 1) * 256 + tc * 4];
    float4 w2 = *(const float4*)&W[(k4 + 2) * 256 + tc * 4];
    float4 w3 = *(const float4*)&W[(k4 + 3) * 256 + tc * 4];
#pragma unroll
    for (int i = 0; i < 16; i++) {
      float4 xv = *(const float4*)&lrow[i * 128 + k4];  // wave-uniform b128 broadcast
      acc[i].x = fmaf(xv.x, w0.x, acc[i].x);
      acc[i].y = fmaf(xv.x, w0.y, acc[i].y);
      acc[i].z = fmaf(xv.x, w0.z, acc[i].z);
      acc[i].w = fmaf(xv.x, w0.w, acc[i].w);
      acc[i].x = fmaf(xv.y, w1.x, acc[i].x);
      acc[i].y = fmaf(xv.y, w1.y, acc[i].y);
      acc[i].z = fmaf(xv.y, w1.z, acc[i].z);
      acc[i].w = fmaf(xv.y, w1.w, acc[i].w);
      acc[i].x = fmaf(xv.z, w2.x, acc[i].x);
      acc[i].y = fmaf(xv.z, w2.y, acc[i].y);
      acc[i].z = fmaf(xv.z, w2.z, acc[i].z);
      acc[i].w = fmaf(xv.z, w2.w, acc[i].w);
      acc[i].x = fmaf(xv.w, w3.x, acc[i].x);
      acc[i].y = fmaf(xv.w, w3.y, acc[i].y);
      acc[i].z = fmaf(xv.w, w3.z, acc[i].z);
      acc[i].w = fmaf(xv.w, w3.w, acc[i].w);
    }
  }
  // epilogue: bf16 store + per-head alpha dots (fp32 accumulators).
  int hh = tc >> 3;            // head 0..7
  int c0 = (tc & 7) * 4;       // channel offset within head
  float4 asv = *(const float4*)&a_src[hh * 32 + c0];
  float4 adv = *(const float4*)&a_dst[hh * 32 + c0];
  bool writer = (tc & 7) == 0;
#pragma unroll
  for (int i = 0; i < 16; i++) {
    int r = row0 + tr * 16 + i;
    float ps = acc[i].x * asv.x;
    ps = fmaf(acc[i].y, asv.y, ps);
    ps = fmaf(acc[i].z, asv.z, ps);
    ps = fmaf(acc[i].w, asv.w, ps);
    float pd = acc[i].x * adv.x;
    pd = fmaf(acc[i].y, adv.y, pd);
    pd = fmaf(acc[i].z, adv.z, pd);
    pd = fmaf(acc[i].w, adv.w, pd);
    ps += __shfl_xor(ps, 1); ps += __shfl_xor(ps, 2); ps += __shfl_xor(ps, 4);
    pd += __shfl_xor(pd, 1); pd += __shfl_xor(pd, 2); pd += __shfl_xor(pd, 4);
    if (r < M) {
      uint2 p;
      p.x = (unsigned)f2bf(acc[i].x) | ((unsigned)f2bf(acc[i].y) << 16);
      p.y = (unsigned)f2bf(acc[i].z) | ((unsigned)f2bf(acc[i].w) << 16);
      *(uint2*)&h1[(size_t)r * 256 + tc * 4] = p;
      if (writer) { a_s1[r * 8 + hh] = ps; a_d1[r * 8 + hh] = pd; }
    }
  }
}

// -------------------- GEMM2 + alpha epilogue --------------------

__global__ __launch_bounds__(256) void gemm2(const float* __restrict__ X,
                                             const float* __restrict__ W,
                                             const float* __restrict__ a_src,
                                             const float* __restrict__ a_dst,
                                             float* __restrict__ h2,
                                             float* __restrict__ a_s2,
                                             float* __restrict__ a_d2, int M) {
  __shared__ float lx[64 * 132];  // padded stride 132
  int row0 = blockIdx.x * 64;
  int tc = threadIdx.x & 7;    // head; cols 4*tc..4*tc+3
  int tr = threadIdx.x >> 3;   // rows tr*2, tr*2+1
  float4 acc[2];
  acc[0] = make_float4(0.f, 0.f, 0.f, 0.f);
  acc[1] = make_float4(0.f, 0.f, 0.f, 0.f);
  for (int kk = 0; kk < 256; kk += 128) {
    __syncthreads();
#pragma unroll
    for (int i = 0; i < 8; i++) {
      int j = threadIdx.x + 256 * i;  // float4 index, 2048 total
      int r = j >> 5;
      int c = (j & 31) * 4;
      float4 v = make_float4(0.f, 0.f, 0.f, 0.f);
      if (row0 + r < M) v = *(const float4*)&X[(size_t)(row0 + r) * 256 + kk + c];
      *(float4*)&lx[r * 132 + c] = v;
    }
    __syncthreads();
    for (int k = 0; k < 128; k++) {
      float4 w4 = *(const float4*)&W[(kk + k) * 32 + tc * 4];
#pragma unroll
      for (int i = 0; i < 2; i++) {
        float xv = lx[(tr * 2 + i) * 132 + k];
        acc[i].x = fmaf(xv, w4.x, acc[i].x);
        acc[i].y = fmaf(xv, w4.y, acc[i].y);
        acc[i].z = fmaf(xv, w4.z, acc[i].z);
        acc[i].w = fmaf(xv, w4.w, acc[i].w);
      }
    }
  }
  float4 asv = *(const float4*)&a_src[tc * 4];
  float4 adv = *(const float4*)&a_dst[tc * 4];
#pragma unroll
  for (int i = 0; i < 2; i++) {
    int r = row0 + tr * 2 + i;
    if (r < M) {
      float ps = acc[i].x * asv.x;
      ps = fmaf(acc[i].y, asv.y, ps);
      ps = fmaf(acc[i].z, asv.z, ps);
      ps = fmaf(acc[i].w, asv.w, ps);
      float pd = acc[i].x * adv.x;
      pd = fmaf(acc[i].y, adv.y, pd);
      pd = fmaf(acc[i].z, adv.z, pd);
      pd = fmaf(acc[i].w, adv.w, pd);
      *(float4*)&h2[(size_t)r * 32 + tc * 4] = acc[i];
      a_s2[r * 8 + tc] = ps;
      a_d2[r * 8 + tc] = pd;
    }
  }
}

// -------------------- segment softmax + aggregation --------------------

// Layer 1: F=256 bf16. One wave per dst; lane owns 4 bf16 (8 B) at channel
// lane*4, head = lane>>3. Single pass (no max subtraction). R2 batching:
// 8 srcs loaded upfront, 8 exps on lanes<8, 8 independent h-gathers in
// flight, then shuffles + FMAs.
__global__ __launch_bounds__(256) void gat_agg_l1(const unsigned short* __restrict__ h,
                                                  const float* __restrict__ asrc,
                                                  const float* __restrict__ adst,
                                                  const int* __restrict__ row_ptr,
                                                  const int* __restrict__ srcs,
                                                  const float* __restrict__ bias,
                                                  float* __restrict__ out, int n) {
  int wave = threadIdx.x >> 6;
  int lane = threadIdx.x & 63;
  int d = blockIdx.x * 4 + wave;
  if (d >= n) return;
  int begin = row_ptr[d];
  int end = row_ptr[d + 1];
  int hh = lane & 7;
  float ad = adst[d * 8 + hh];

  const int myhead = lane >> 3;
  float denom = 0.f;
  float4 acc = make_float4(0.f, 0.f, 0.f, 0.f);
  int e = begin;
  for (; e + 8 <= end; e += 8) {
    int s0 = srcs[e + 0], s1 = srcs[e + 1], s2 = srcs[e + 2], s3 = srcs[e + 3];
    int s4 = srcs[e + 4], s5 = srcs[e + 5], s6 = srcs[e + 6], s7 = srcs[e + 7];
    float w0 = 0.f, w1 = 0.f, w2 = 0.f, w3 = 0.f;
    float w4 = 0.f, w5 = 0.f, w6 = 0.f, w7 = 0.f;
    if (lane < 8) {
      w0 = __expf(lrelu(asrc[s0 * 8 + lane] + ad));
      w1 = __expf(lrelu(asrc[s1 * 8 + lane] + ad));
      w2 = __expf(lrelu(asrc[s2 * 8 + lane] + ad));
      w3 = __expf(lrelu(asrc[s3 * 8 + lane] + ad));
      w4 = __expf(lrelu(asrc[s4 * 8 + lane] + ad));
      w5 = __expf(lrelu(asrc[s5 * 8 + lane] + ad));
      w6 = __expf(lrelu(asrc[s6 * 8 + lane] + ad));
      w7 = __expf(lrelu(asrc[s7 * 8 + lane] + ad));
      denom += (w0 + w1 + w2 + w3) + (w4 + w5 + w6 + w7);
    }
    uint2 q0 = *(const uint2*)&h[(size_t)s0 * 256 + lane * 4];
    uint2 q1 = *(const uint2*)&h[(size_t)s1 * 256 + lane * 4];
    uint2 q2 = *(const uint2*)&h[(size_t)s2 * 256 + lane * 4];
    uint2 q3 = *(const uint2*)&h[(size_t)s3 * 256 + lane * 4];
    uint2 q4 = *(const uint2*)&h[(size_t)s4 * 256 + lane * 4];
    uint2 q5 = *(const uint2*)&h[(size_t)s5 * 256 + lane * 4];
    uint2 q6 = *(const uint2*)&h[(size_t)s6 * 256 + lane * 4];
    uint2 q7 = *(const uint2*)&h[(size_t)s7 * 256 + lane * 4];
    float f0 = __shfl(w0, myhead), f1 = __shfl(w1, myhead);
    float f2 = __shfl(w2, myhead), f3 = __shfl(w3, myhead);
    float f4 = __shfl(w4, myhead), f5 = __shfl(w5, myhead);
    float f6 = __shfl(w6, myhead), f7 = __shfl(w7, myhead);
#define ACC4(ff, qq)                                      \
    acc.x = fmaf(ff, bf_lo(qq.x), acc.x);                 \
    acc.y = fmaf(ff, bf_hi(qq.x), acc.y);                 \
    acc.z = fmaf(ff, bf_lo(qq.y), acc.z);                 \
    acc.w = fmaf(ff, bf_hi(qq.y), acc.w);
    ACC4(f0, q0) ACC4(f1, q1) ACC4(f2, q2) ACC4(f3, q3)
    ACC4(f4, q4) ACC4(f5, q5) ACC4(f6, q6) ACC4(f7, q7)
  }
  for (; e < end; ++e) {
    int s = srcs[e];
    float w = 0.f;
    if (lane < 8) {
      w = __expf(lrelu(asrc[s * 8 + lane] + ad));
      denom += w;
    }
    float wh = __shfl(w, myhead);
    uint2 q = *(const uint2*)&h[(size_t)s * 256 + lane * 4];
    ACC4(wh, q)
  }
#undef ACC4
  float dn = __shfl(denom, myhead) + 1e-16f;
  float inv = 1.f / dn;
  int f = lane * 4;
  float4 bv = *(const float4*)&bias[f];
  float4 r;
  r.x = lrelu(acc.x * inv + bv.x);
  r.y = lrelu(acc.y * inv + bv.y);
  r.z = lrelu(acc.z * inv + bv.z);
  r.w = lrelu(acc.w * inv + bv.w);
  *(float4*)&out[(size_t)d * 256 + f] = r;
}

// Layer 2: C=4, F=32. One wave per dst; 8 edges in parallel
// (lane = edge-group*8 + head). Single pass, no max subtraction.
__global__ __launch_bounds__(256) void gat_agg_l2(const float* __restrict__ h,
                                                  const float* __restrict__ asrc,
                                                  const float* __restrict__ adst,
                                                  const int* __restrict__ row_ptr,
                                                  const int* __restrict__ srcs,
                                                  const float* __restrict__ bias,
                                                  float* __restrict__ out, int n) {
  int wave = threadIdx.x >> 6;
  int lane = threadIdx.x & 63;
  int d = blockIdx.x * 4 + wave;
  if (d >= n) return;
  int begin = row_ptr[d];
  int end = row_ptr[d + 1];
  int hh = lane & 7;
  int eg = lane >> 3;
  float ad = adst[d * 8 + hh];

  float denom = 0.f;
  float4 acc = make_float4(0.f, 0.f, 0.f, 0.f);
  for (int base = begin; base < end; base += 8) {
    int e = base + eg;
    if (e < end) {
      int s = srcs[e];
      float w = __expf(lrelu(asrc[s * 8 + hh] + ad));
      denom += w;
      const float4 hv = *(const float4*)&h[(size_t)s * 32 + hh * 4];
      acc.x = fmaf(w, hv.x, acc.x);
      acc.y = fmaf(w, hv.y, acc.y);
      acc.z = fmaf(w, hv.z, acc.z);
      acc.w = fmaf(w, hv.w, acc.w);
    }
  }
#pragma unroll
  for (int mask = 8; mask <= 32; mask <<= 1) {
    denom += __shfl_xor(denom, mask);
    acc.x += __shfl_xor(acc.x, mask);
    acc.y += __shfl_xor(acc.y, mask);
    acc.z += __shfl_xor(acc.z, mask);
    acc.w += __shfl_xor(acc.w, mask);
  }
  if (lane < 8) {
    float inv = 1.f / (denom + 1e-16f);
    int f = lane * 4;
    float4 bv = *(const float4*)&bias[f];
    float4 r;
    r.x = acc.x * inv + bv.x;
    r.y = acc.y * inv + bv.y;
    r.z = acc.z * inv + bv.z;
    r.w = acc.w * inv + bv.w;
    *(float4*)&out[(size_t)d * 32 + f] = r;
  }
}

// -------------------- launcher --------------------

extern "C" void kernel_launch(void* const* d_in, const int* in_sizes, int n_in,
                              void* d_out, int out_size, void* d_ws, size_t ws_size,
                              hipStream_t stream) {
  const float* x   = (const float*)d_in[0];
  const int*   ei  = (const int*)d_in[1];
  const float* W1  = (const float*)d_in[2];
  const float* as1 = (const float*)d_in[3];
  const float* ad1 = (const float*)d_in[4];
  const float* b1  = (const float*)d_in[5];
  const float* W2  = (const float*)d_in[6];
  const float* as2 = (const float*)d_in[7];
  const float* ad2 = (const float*)d_in[8];
  const float* b2  = (const float*)d_in[9];
  float* out = (float*)d_out;

  const int E = in_sizes[1] / 2;
  const int n = in_sizes[0] / 128;
  const int* srce = ei;
  const int* dste = ei + E;

  char* ws = (char*)d_ws;
  size_t off = 0;
  auto alloc = [&](size_t bytes) -> void* {
    void* p = ws + off;
    off = (off + bytes + 255) & ~(size_t)255;
    return p;
  };
  int* cnt      = (int*)alloc((size_t)n * 4);
  int* row_ptr  = (int*)alloc((size_t)(n + 1) * 4);
  int* cursor   = (int*)alloc((size_t)n * 4);
  int* bsum     = (int*)alloc(256 * 4);
  int* boff     = (int*)alloc(256 * 4);
  int* srcs     = (int*)alloc((size_t)(E + n) * 4);
  unsigned short* h1 = (unsigned short*)alloc((size_t)n * 256 * 2);  // bf16
  float* a_s1   = (float*)alloc((size_t)n * 8 * 4);
  float* a_d1   = (float*)alloc((size_t)n * 8 * 4);
  float* x2     = (float*)alloc((size_t)n * 256 * 4);
  float* h2     = (float*)alloc((size_t)n * 32 * 4);
  float* a_s2   = (float*)alloc((size_t)n * 8 * 4);
  float* a_d2   = (float*)alloc((size_t)n * 8 * 4);

  const int tot = E + n;
  hipMemsetAsync(cnt, 0, (size_t)n * 4, stream);
  k_hist<<<(tot + 255) / 256, 256, 0, stream>>>(dste, E, n, cnt);
  const int nb = (n + 1023) / 1024;
  k_scan1<<<nb, 256, 0, stream>>>(cnt, n, bsum);
  k_scan2<<<1, 64, 0, stream>>>(bsum, nb, boff, row_ptr, n);
  k_scan3<<<nb, 256, 0, stream>>>(cnt, boff, n, row_ptr, cursor);
  k_scatter<<<(tot + 255) / 256, 256, 0, stream>>>(srce, dste, E, n, cursor, srcs);

  gemm1<<<(n + 63) / 64, 256, 0, stream>>>(x, W1, as1, ad1, h1, a_s1, a_d1, n);
  gat_agg_l1<<<(n + 3) / 4, 256, 0, stream>>>(h1, a_s1, a_d1, row_ptr, srcs, b1, x2, n);

  gemm2<<<(n + 63) / 64, 256, 0, stream>>>(x2, W2, as2, ad2, h2, a_s2, a_d2, n);
  gat_agg_l2<<<(n + 3) / 4, 256, 0, stream>>>(h2, a_s2, a_d2, row_ptr, srcs, b2, out, n);
}

// Round 6
// 378.205 us; speedup vs baseline: 1.0741x; 1.0160x over previous
//
#include <hip/hip_runtime.h>
#include <hip/hip_bf16.h>
#include <cstdint>
#include <cstddef>

// ---------------------------------------------------------------------------
// GAT 2-layer forward. N=50000, E=800000 (+N self loops), H=8 heads.
// Layer1: Fin=128 -> 8x32 (=256), lrelu(0.2). Layer2: 256 -> 8x4 (=32).
// R5: (a) gemm1 moved to bf16 MFMA (16x16x32, 4x4 register blocking,
// 8 ds_read_b128 : 16 MFMA); alphas split into calc_alpha kernel reading
// bf16 h1; (b) x2 stored bf16 (halves gemm2 read); (c) agg_l2 edge loop
// unrolled x2 with upfront batched loads (R4 lesson). agg_l1 untouched
// (proven 80.7 us).
// ---------------------------------------------------------------------------

__device__ __forceinline__ float lrelu(float a) { return a > 0.f ? a : 0.2f * a; }

__device__ __forceinline__ unsigned short f2bf(float f) {
  unsigned u = __float_as_uint(f);
  unsigned r = (u + 0x7fff + ((u >> 16) & 1)) >> 16;  // RNE
  return (unsigned short)r;
}
__device__ __forceinline__ float bf_lo(unsigned q) { return __uint_as_float(q << 16); }
__device__ __forceinline__ float bf_hi(unsigned q) { return __uint_as_float(q & 0xffff0000u); }

typedef __attribute__((ext_vector_type(8))) short bf16x8;
typedef __attribute__((ext_vector_type(4))) float f32x4;

// -------------------- CSR build --------------------

__global__ __launch_bounds__(256) void k_hist(const int* __restrict__ dste, int E, int n,
                                              int* __restrict__ cnt) {
  int t = blockIdx.x * 256 + threadIdx.x;
  if (t >= E + n) return;
  int d = (t < E) ? dste[t] : (t - E);   // self-loop for node t-E
  atomicAdd(&cnt[d], 1);
}

__global__ __launch_bounds__(256) void k_scan1(const int* __restrict__ cnt, int n,
                                               int* __restrict__ bsum) {
  __shared__ int sb[256];
  int i0 = blockIdx.x * 1024 + threadIdx.x * 4;
  int s = 0;
#pragma unroll
  for (int j = 0; j < 4; j++) { int i = i0 + j; if (i < n) s += cnt[i]; }
  sb[threadIdx.x] = s;
  __syncthreads();
  for (int off = 128; off > 0; off >>= 1) {
    if (threadIdx.x < off) sb[threadIdx.x] += sb[threadIdx.x + off];
    __syncthreads();
  }
  if (threadIdx.x == 0) bsum[blockIdx.x] = sb[0];
}

__global__ void k_scan2(const int* __restrict__ bsum, int nb, int* __restrict__ boff,
                        int* __restrict__ row_ptr, int n) {
  if (threadIdx.x == 0 && blockIdx.x == 0) {
    int run = 0;
    for (int j = 0; j < nb; j++) { boff[j] = run; run += bsum[j]; }
    row_ptr[n] = run;
  }
}

__global__ __launch_bounds__(256) void k_scan3(const int* __restrict__ cnt,
                                               const int* __restrict__ boff, int n,
                                               int* __restrict__ row_ptr,
                                               int* __restrict__ cursor) {
  __shared__ int sb[256];
  int i0 = blockIdx.x * 1024 + threadIdx.x * 4;
  int c[4];
  int s = 0;
#pragma unroll
  for (int j = 0; j < 4; j++) { int i = i0 + j; c[j] = (i < n) ? cnt[i] : 0; s += c[j]; }
  sb[threadIdx.x] = s;
  __syncthreads();
  for (int off = 1; off < 256; off <<= 1) {
    int add = (threadIdx.x >= off) ? sb[threadIdx.x - off] : 0;
    __syncthreads();
    sb[threadIdx.x] += add;
    __syncthreads();
  }
  int excl = sb[threadIdx.x] - s + boff[blockIdx.x];
#pragma unroll
  for (int j = 0; j < 4; j++) {
    int i = i0 + j;
    if (i < n) { row_ptr[i] = excl; cursor[i] = excl; excl += c[j]; }
  }
}

__global__ __launch_bounds__(256) void k_scatter(const int* __restrict__ srce,
                                                 const int* __restrict__ dste, int E, int n,
                                                 int* __restrict__ cursor,
                                                 int* __restrict__ srcs) {
  int t = blockIdx.x * 256 + threadIdx.x;
  if (t >= E + n) return;
  int s, d;
  if (t < E) { s = srce[t]; d = dste[t]; } else { s = d = t - E; }
  int pos = atomicAdd(&cursor[d], 1);
  srcs[pos] = s;
}

// -------------------- GEMM1: bf16 MFMA --------------------

// X[M,128] fp32 @ W[128,256] fp32 -> h1 bf16 [M,256]. Block: 64 rows, 256 thr
// (4 waves); wave w owns 64-col slab. 4x4 16x16 acc tiles per wave; K split
// into two 64-chunks (B-tile restaged per chunk). A: [64][136] bf16 (pad 8
// -> row stride 68 dw == 4 banks, 2-way free). B^T: [256][72] bf16.
__global__ __launch_bounds__(256) void gemm1_mfma(const float* __restrict__ X,
                                                  const float* __restrict__ W,
                                                  unsigned short* __restrict__ h1,
                                                  int M) {
  __shared__ unsigned short As[64 * 136];
  __shared__ unsigned short Bs[256 * 72];
  const int row0 = blockIdx.x * 64;
  const int tid = threadIdx.x;
  const int wv = tid >> 6, lane = tid & 63;
  const int quad = lane >> 4, l15 = lane & 15;
  const int colw = wv * 64;

  // stage A (full K): 2048 float4 / 256 thr = 8 each
#pragma unroll
  for (int i = 0; i < 8; i++) {
    int j = tid + 256 * i;
    int r = j >> 5;
    int c4 = (j & 31) * 4;
    float4 v = make_float4(0.f, 0.f, 0.f, 0.f);
    if (row0 + r < M) v = *(const float4*)&X[(size_t)(row0 + r) * 128 + c4];
    unsigned short* dst = &As[r * 136 + c4];
    dst[0] = f2bf(v.x); dst[1] = f2bf(v.y); dst[2] = f2bf(v.z); dst[3] = f2bf(v.w);
  }

  f32x4 acc[16];
#pragma unroll
  for (int i = 0; i < 16; i++) acc[i] = (f32x4)0.f;

  for (int kc = 0; kc < 128; kc += 64) {
    __syncthreads();
    // stage Bs = W[kc..kc+64][0..256]^T : 4096 float4 / 256 thr = 16 each
#pragma unroll
    for (int i = 0; i < 16; i++) {
      int j = tid + 256 * i;
      int k = j >> 6;
      int n4 = (j & 63) * 4;
      float4 v = *(const float4*)&W[(size_t)(kc + k) * 256 + n4];
      Bs[(n4 + 0) * 72 + k] = f2bf(v.x);
      Bs[(n4 + 1) * 72 + k] = f2bf(v.y);
      Bs[(n4 + 2) * 72 + k] = f2bf(v.z);
      Bs[(n4 + 3) * 72 + k] = f2bf(v.w);
    }
    __syncthreads();
#pragma unroll
    for (int ks = 0; ks < 64; ks += 32) {
      bf16x8 af[4], bfr[4];
#pragma unroll
      for (int mi = 0; mi < 4; mi++)
        af[mi] = *(const bf16x8*)&As[(mi * 16 + l15) * 136 + kc + ks + quad * 8];
#pragma unroll
      for (int ni = 0; ni < 4; ni++)
        bfr[ni] = *(const bf16x8*)&Bs[(colw + ni * 16 + l15) * 72 + ks + quad * 8];
#pragma unroll
      for (int mi = 0; mi < 4; mi++)
#pragma unroll
        for (int ni = 0; ni < 4; ni++)
          acc[mi * 4 + ni] = __builtin_amdgcn_mfma_f32_16x16x32_bf16(
              af[mi], bfr[ni], acc[mi * 4 + ni], 0, 0, 0);
    }
  }
  // epilogue: D[m][n]: m = mi*16 + quad*4 + r, n = colw + ni*16 + l15
#pragma unroll
  for (int mi = 0; mi < 4; mi++) {
#pragma unroll
    for (int r = 0; r < 4; r++) {
      int m = row0 + mi * 16 + quad * 4 + r;
      if (m < M) {
#pragma unroll
        for (int ni = 0; ni < 4; ni++)
          h1[(size_t)m * 256 + colw + ni * 16 + l15] = f2bf(acc[mi * 4 + ni][r]);
      }
    }
  }
}

// -------------------- attention logits (bf16 h1) --------------------

__global__ __launch_bounds__(256) void calc_alpha_bf(const unsigned short* __restrict__ h,
                                                     const float* __restrict__ a_src,
                                                     const float* __restrict__ a_dst,
                                                     float* __restrict__ asrc,
                                                     float* __restrict__ adst, int n) {
  int t = blockIdx.x * 256 + threadIdx.x;
  if (t >= n * 8) return;
  int node = t >> 3, hh = t & 7;
  const unsigned short* hp = h + (size_t)node * 256 + hh * 32;
  const float* as = a_src + hh * 32;
  const float* ad = a_dst + hh * 32;
  float s1 = 0.f, s2 = 0.f;
#pragma unroll
  for (int c = 0; c < 32; c += 4) {
    uint2 q = *(const uint2*)&hp[c];
    float v0 = bf_lo(q.x), v1 = bf_hi(q.x), v2 = bf_lo(q.y), v3 = bf_hi(q.y);
    s1 = fmaf(v0, as[c], s1); s1 = fmaf(v1, as[c + 1], s1);
    s1 = fmaf(v2, as[c + 2], s1); s1 = fmaf(v3, as[c + 3], s1);
    s2 = fmaf(v0, ad[c], s2); s2 = fmaf(v1, ad[c + 1], s2);
    s2 = fmaf(v2, ad[c + 2], s2); s2 = fmaf(v3, ad[c + 3], s2);
  }
  asrc[t] = s1;
  adst[t] = s2;
}

// -------------------- GEMM2 + alpha epilogue (x2 in bf16) --------------------

__global__ __launch_bounds__(256) void gemm2(const unsigned short* __restrict__ Xb,
                                             const float* __restrict__ W,
                                             const float* __restrict__ a_src,
                                             const float* __restrict__ a_dst,
                                             float* __restrict__ h2,
                                             float* __restrict__ a_s2,
                                             float* __restrict__ a_d2, int M) {
  __shared__ float lx[64 * 132];  // padded stride 132
  int row0 = blockIdx.x * 64;
  int tc = threadIdx.x & 7;    // head; cols 4*tc..4*tc+3
  int tr = threadIdx.x >> 3;   // rows tr*2, tr*2+1
  float4 acc[2];
  acc[0] = make_float4(0.f, 0.f, 0.f, 0.f);
  acc[1] = make_float4(0.f, 0.f, 0.f, 0.f);
  for (int kk = 0; kk < 256; kk += 128) {
    __syncthreads();
#pragma unroll
    for (int i = 0; i < 8; i++) {
      int j = threadIdx.x + 256 * i;  // 4-elem group index, 2048 total
      int r = j >> 5;
      int c = (j & 31) * 4;
      float4 v = make_float4(0.f, 0.f, 0.f, 0.f);
      if (row0 + r < M) {
        uint2 q = *(const uint2*)&Xb[(size_t)(row0 + r) * 256 + kk + c];
        v = make_float4(bf_lo(q.x), bf_hi(q.x), bf_lo(q.y), bf_hi(q.y));
      }
      *(float4*)&lx[r * 132 + c] = v;
    }
    __syncthreads();
    for (int k = 0; k < 128; k++) {
      float4 w4 = *(const float4*)&W[(kk + k) * 32 + tc * 4];
#pragma unroll
      for (int i = 0; i < 2; i++) {
        float xv = lx[(tr * 2 + i) * 132 + k];
        acc[i].x = fmaf(xv, w4.x, acc[i].x);
        acc[i].y = fmaf(xv, w4.y, acc[i].y);
        acc[i].z = fmaf(xv, w4.z, acc[i].z);
        acc[i].w = fmaf(xv, w4.w, acc[i].w);
      }
    }
  }
  float4 asv = *(const float4*)&a_src[tc * 4];
  float4 adv = *(const float4*)&a_dst[tc * 4];
#pragma unroll
  for (int i = 0; i < 2; i++) {
    int r = row0 + tr * 2 + i;
    if (r < M) {
      float ps = acc[i].x * asv.x;
      ps = fmaf(acc[i].y, asv.y, ps);
      ps = fmaf(acc[i].z, asv.z, ps);
      ps = fmaf(acc[i].w, asv.w, ps);
      float pd = acc[i].x * adv.x;
      pd = fmaf(acc[i].y, adv.y, pd);
      pd = fmaf(acc[i].z, adv.z, pd);
      pd = fmaf(acc[i].w, adv.w, pd);
      *(float4*)&h2[(size_t)r * 32 + tc * 4] = acc[i];
      a_s2[r * 8 + tc] = ps;
      a_d2[r * 8 + tc] = pd;
    }
  }
}

// -------------------- segment softmax + aggregation --------------------

// Layer 1: F=256 bf16 in, bf16 out (x2). R2 batching, single-pass softmax.
__global__ __launch_bounds__(256) void gat_agg_l1(const unsigned short* __restrict__ h,
                                                  const float* __restrict__ asrc,
                                                  const float* __restrict__ adst,
                                                  const int* __restrict__ row_ptr,
                                                  const int* __restrict__ srcs,
                                                  const float* __restrict__ bias,
                                                  unsigned short* __restrict__ out, int n) {
  int wave = threadIdx.x >> 6;
  int lane = threadIdx.x & 63;
  int d = blockIdx.x * 4 + wave;
  if (d >= n) return;
  int begin = row_ptr[d];
  int end = row_ptr[d + 1];
  int hh = lane & 7;
  float ad = adst[d * 8 + hh];

  const int myhead = lane >> 3;
  float denom = 0.f;
  float4 acc = make_float4(0.f, 0.f, 0.f, 0.f);
  int e = begin;
  for (; e + 8 <= end; e += 8) {
    int s0 = srcs[e + 0], s1 = srcs[e + 1], s2 = srcs[e + 2], s3 = srcs[e + 3];
    int s4 = srcs[e + 4], s5 = srcs[e + 5], s6 = srcs[e + 6], s7 = srcs[e + 7];
    float w0 = 0.f, w1 = 0.f, w2 = 0.f, w3 = 0.f;
    float w4 = 0.f, w5 = 0.f, w6 = 0.f, w7 = 0.f;
    if (lane < 8) {
      w0 = __expf(lrelu(asrc[s0 * 8 + lane] + ad));
      w1 = __expf(lrelu(asrc[s1 * 8 + lane] + ad));
      w2 = __expf(lrelu(asrc[s2 * 8 + lane] + ad));
      w3 = __expf(lrelu(asrc[s3 * 8 + lane] + ad));
      w4 = __expf(lrelu(asrc[s4 * 8 + lane] + ad));
      w5 = __expf(lrelu(asrc[s5 * 8 + lane] + ad));
      w6 = __expf(lrelu(asrc[s6 * 8 + lane] + ad));
      w7 = __expf(lrelu(asrc[s7 * 8 + lane] + ad));
      denom += (w0 + w1 + w2 + w3) + (w4 + w5 + w6 + w7);
    }
    uint2 q0 = *(const uint2*)&h[(size_t)s0 * 256 + lane * 4];
    uint2 q1 = *(const uint2*)&h[(size_t)s1 * 256 + lane * 4];
    uint2 q2 = *(const uint2*)&h[(size_t)s2 * 256 + lane * 4];
    uint2 q3 = *(const uint2*)&h[(size_t)s3 * 256 + lane * 4];
    uint2 q4 = *(const uint2*)&h[(size_t)s4 * 256 + lane * 4];
    uint2 q5 = *(const uint2*)&h[(size_t)s5 * 256 + lane * 4];
    uint2 q6 = *(const uint2*)&h[(size_t)s6 * 256 + lane * 4];
    uint2 q7 = *(const uint2*)&h[(size_t)s7 * 256 + lane * 4];
    float f0 = __shfl(w0, myhead), f1 = __shfl(w1, myhead);
    float f2 = __shfl(w2, myhead), f3 = __shfl(w3, myhead);
    float f4 = __shfl(w4, myhead), f5 = __shfl(w5, myhead);
    float f6 = __shfl(w6, myhead), f7 = __shfl(w7, myhead);
#define ACC4(ff, qq)                                      \
    acc.x = fmaf(ff, bf_lo(qq.x), acc.x);                 \
    acc.y = fmaf(ff, bf_hi(qq.x), acc.y);                 \
    acc.z = fmaf(ff, bf_lo(qq.y), acc.z);                 \
    acc.w = fmaf(ff, bf_hi(qq.y), acc.w);
    ACC4(f0, q0) ACC4(f1, q1) ACC4(f2, q2) ACC4(f3, q3)
    ACC4(f4, q4) ACC4(f5, q5) ACC4(f6, q6) ACC4(f7, q7)
  }
  for (; e < end; ++e) {
    int s = srcs[e];
    float w = 0.f;
    if (lane < 8) {
      w = __expf(lrelu(asrc[s * 8 + lane] + ad));
      denom += w;
    }
    float wh = __shfl(w, myhead);
    uint2 q = *(const uint2*)&h[(size_t)s * 256 + lane * 4];
    ACC4(wh, q)
  }
#undef ACC4
  float dn = __shfl(denom, myhead) + 1e-16f;
  float inv = 1.f / dn;
  int f = lane * 4;
  float4 bv = *(const float4*)&bias[f];
  float rx = lrelu(acc.x * inv + bv.x);
  float ry = lrelu(acc.y * inv + bv.y);
  float rz = lrelu(acc.z * inv + bv.z);
  float rw = lrelu(acc.w * inv + bv.w);
  uint2 p;
  p.x = (unsigned)f2bf(rx) | ((unsigned)f2bf(ry) << 16);
  p.y = (unsigned)f2bf(rz) | ((unsigned)f2bf(rw) << 16);
  *(uint2*)&out[(size_t)d * 256 + f] = p;
}

// Layer 2: C=4, F=32. 8 edges in parallel per wave, unrolled x2 (16 edges
// per iter, 2 loads in flight per lane). Single pass.
__global__ __launch_bounds__(256) void gat_agg_l2(const float* __restrict__ h,
                                                  const float* __restrict__ asrc,
                                                  const float* __restrict__ adst,
                                                  const int* __restrict__ row_ptr,
                                                  const int* __restrict__ srcs,
                                                  const float* __restrict__ bias,
                                                  float* __restrict__ out, int n) {
  int wave = threadIdx.x >> 6;
  int lane = threadIdx.x & 63;
  int d = blockIdx.x * 4 + wave;
  if (d >= n) return;
  int begin = row_ptr[d];
  int end = row_ptr[d + 1];
  int hh = lane & 7;
  int eg = lane >> 3;
  float ad = adst[d * 8 + hh];

  float denom = 0.f;
  float4 acc = make_float4(0.f, 0.f, 0.f, 0.f);
  int base = begin;
  for (; base + 16 <= end; base += 16) {
    int sA = srcs[base + eg];
    int sB = srcs[base + 8 + eg];
    float aA = asrc[sA * 8 + hh];
    float aB = asrc[sB * 8 + hh];
    const float4 hA = *(const float4*)&h[(size_t)sA * 32 + hh * 4];
    const float4 hB = *(const float4*)&h[(size_t)sB * 32 + hh * 4];
    float wA = __expf(lrelu(aA + ad));
    float wB = __expf(lrelu(aB + ad));
    denom += wA + wB;
    acc.x = fmaf(wA, hA.x, acc.x); acc.y = fmaf(wA, hA.y, acc.y);
    acc.z = fmaf(wA, hA.z, acc.z); acc.w = fmaf(wA, hA.w, acc.w);
    acc.x = fmaf(wB, hB.x, acc.x); acc.y = fmaf(wB, hB.y, acc.y);
    acc.z = fmaf(wB, hB.z, acc.z); acc.w = fmaf(wB, hB.w, acc.w);
  }
  for (; base < end; base += 8) {
    int e = base + eg;
    if (e < end) {
      int s = srcs[e];
      float w = __expf(lrelu(asrc[s * 8 + hh] + ad));
      denom += w;
      const float4 hv = *(const float4*)&h[(size_t)s * 32 + hh * 4];
      acc.x = fmaf(w, hv.x, acc.x);
      acc.y = fmaf(w, hv.y, acc.y);
      acc.z = fmaf(w, hv.z, acc.z);
      acc.w = fmaf(w, hv.w, acc.w);
    }
  }
#pragma unroll
  for (int mask = 8; mask <= 32; mask <<= 1) {
    denom += __shfl_xor(denom, mask);
    acc.x += __shfl_xor(acc.x, mask);
    acc.y += __shfl_xor(acc.y, mask);
    acc.z += __shfl_xor(acc.z, mask);
    acc.w += __shfl_xor(acc.w, mask);
  }
  if (lane < 8) {
    float inv = 1.f / (denom + 1e-16f);
    int f = lane * 4;
    float4 bv = *(const float4*)&bias[f];
    float4 r;
    r.x = acc.x * inv + bv.x;
    r.y = acc.y * inv + bv.y;
    r.z = acc.z * inv + bv.z;
    r.w = acc.w * inv + bv.w;
    *(float4*)&out[(size_t)d * 32 + f] = r;
  }
}

// -------------------- launcher --------------------

extern "C" void kernel_launch(void* const* d_in, const int* in_sizes, int n_in,
                              void* d_out, int out_size, void* d_ws, size_t ws_size,
                              hipStream_t stream) {
  const float* x   = (const float*)d_in[0];
  const int*   ei  = (const int*)d_in[1];
  const float* W1  = (const float*)d_in[2];
  const float* as1 = (const float*)d_in[3];
  const float* ad1 = (const float*)d_in[4];
  const float* b1  = (const float*)d_in[5];
  const float* W2  = (const float*)d_in[6];
  const float* as2 = (const float*)d_in[7];
  const float* ad2 = (const float*)d_in[8];
  const float* b2  = (const float*)d_in[9];
  float* out = (float*)d_out;

  const int E = in_sizes[1] / 2;
  const int n = in_sizes[0] / 128;
  const int* srce = ei;
  const int* dste = ei + E;

  char* ws = (char*)d_ws;
  size_t off = 0;
  auto alloc = [&](size_t bytes) -> void* {
    void* p = ws + off;
    off = (off + bytes + 255) & ~(size_t)255;
    return p;
  };
  int* cnt      = (int*)alloc((size_t)n * 4);
  int* row_ptr  = (int*)alloc((size_t)(n + 1) * 4);
  int* cursor   = (int*)alloc((size_t)n * 4);
  int* bsum     = (int*)alloc(256 * 4);
  int* boff     = (int*)alloc(256 * 4);
  int* srcs     = (int*)alloc((size_t)(E + n) * 4);
  unsigned short* h1 = (unsigned short*)alloc((size_t)n * 256 * 2);  // bf16
  float* a_s1   = (float*)alloc((size_t)n * 8 * 4);
  float* a_d1   = (float*)alloc((size_t)n * 8 * 4);
  unsigned short* x2 = (unsigned short*)alloc((size_t)n * 256 * 2);  // bf16
  float* h2     = (float*)alloc((size_t)n * 32 * 4);
  float* a_s2   = (float*)alloc((size_t)n * 8 * 4);
  float* a_d2   = (float*)alloc((size_t)n * 8 * 4);

  const int tot = E + n;
  hipMemsetAsync(cnt, 0, (size_t)n * 4, stream);
  k_hist<<<(tot + 255) / 256, 256, 0, stream>>>(dste, E, n, cnt);
  const int nb = (n + 1023) / 1024;
  k_scan1<<<nb, 256, 0, stream>>>(cnt, n, bsum);
  k_scan2<<<1, 64, 0, stream>>>(bsum, nb, boff, row_ptr, n);
  k_scan3<<<nb, 256, 0, stream>>>(cnt, boff, n, row_ptr, cursor);
  k_scatter<<<(tot + 255) / 256, 256, 0, stream>>>(srce, dste, E, n, cursor, srcs);

  gemm1_mfma<<<(n + 63) / 64, 256, 0, stream>>>(x, W1, h1, n);
  calc_alpha_bf<<<(n * 8 + 255) / 256, 256, 0, stream>>>(h1, as1, ad1, a_s1, a_d1, n);
  gat_agg_l1<<<(n + 3) / 4, 256, 0, stream>>>(h1, a_s1, a_d1, row_ptr, srcs, b1, x2, n);

  gemm2<<<(n + 63) / 64, 256, 0, stream>>>(x2, W2, as2, ad2, h2, a_s2, a_d2, n);
  gat_agg_l2<<<(n + 3) / 4, 256, 0, stream>>>(h2, a_s2, a_d2, row_ptr, srcs, b2, out, n);
}

// Round 7
// 332.564 us; speedup vs baseline: 1.2215x; 1.1372x over previous
//
#include <hip/hip_runtime.h>
#include <hip/hip_bf16.h>
#include <cstdint>
#include <cstddef>

// ---------------------------------------------------------------------------
// GAT 2-layer forward. N=50000, E=800000 (+N self loops), H=8 heads.
// Layer1: Fin=128 -> 8x32 (=256), lrelu(0.2). Layer2: 256 -> 8x4 (=32).
// R6: (a) W1 pre-transposed to bf16 once (k_w1t); gemm1 stages B via
// ds_write_b128 (no per-block convert/transpose) and A via packed b64 —
// R5's scalar b16 staging ate the MFMA win; (b) alpha dots fused into the
// gemm1 epilogue (calc_alpha kernel + 25.6MB re-read eliminated);
// (c) agg_l1: 16 gathers in flight + 2 independent acc chains, predicated
// batch tail (serial scalar tail eliminated).
// ---------------------------------------------------------------------------

__device__ __forceinline__ float lrelu(float a) { return a > 0.f ? a : 0.2f * a; }

__device__ __forceinline__ unsigned short f2bf(float f) {
  unsigned u = __float_as_uint(f);
  unsigned r = (u + 0x7fff + ((u >> 16) & 1)) >> 16;  // RNE
  return (unsigned short)r;
}
__device__ __forceinline__ float bf_lo(unsigned q) { return __uint_as_float(q << 16); }
__device__ __forceinline__ float bf_hi(unsigned q) { return __uint_as_float(q & 0xffff0000u); }

typedef __attribute__((ext_vector_type(8))) short bf16x8;
typedef __attribute__((ext_vector_type(4))) float f32x4;

// -------------------- CSR build --------------------

__global__ __launch_bounds__(256) void k_hist(const int* __restrict__ dste, int E, int n,
                                              int* __restrict__ cnt) {
  int t = blockIdx.x * 256 + threadIdx.x;
  if (t >= E + n) return;
  int d = (t < E) ? dste[t] : (t - E);   // self-loop for node t-E
  atomicAdd(&cnt[d], 1);
}

__global__ __launch_bounds__(256) void k_scan1(const int* __restrict__ cnt, int n,
                                               int* __restrict__ bsum) {
  __shared__ int sb[256];
  int i0 = blockIdx.x * 1024 + threadIdx.x * 4;
  int s = 0;
#pragma unroll
  for (int j = 0; j < 4; j++) { int i = i0 + j; if (i < n) s += cnt[i]; }
  sb[threadIdx.x] = s;
  __syncthreads();
  for (int off = 128; off > 0; off >>= 1) {
    if (threadIdx.x < off) sb[threadIdx.x] += sb[threadIdx.x + off];
    __syncthreads();
  }
  if (threadIdx.x == 0) bsum[blockIdx.x] = sb[0];
}

__global__ void k_scan2(const int* __restrict__ bsum, int nb, int* __restrict__ boff,
                        int* __restrict__ row_ptr, int n) {
  if (threadIdx.x == 0 && blockIdx.x == 0) {
    int run = 0;
    for (int j = 0; j < nb; j++) { boff[j] = run; run += bsum[j]; }
    row_ptr[n] = run;
  }
}

__global__ __launch_bounds__(256) void k_scan3(const int* __restrict__ cnt,
                                               const int* __restrict__ boff, int n,
                                               int* __restrict__ row_ptr,
                                               int* __restrict__ cursor) {
  __shared__ int sb[256];
  int i0 = blockIdx.x * 1024 + threadIdx.x * 4;
  int c[4];
  int s = 0;
#pragma unroll
  for (int j = 0; j < 4; j++) { int i = i0 + j; c[j] = (i < n) ? cnt[i] : 0; s += c[j]; }
  sb[threadIdx.x] = s;
  __syncthreads();
  for (int off = 1; off < 256; off <<= 1) {
    int add = (threadIdx.x >= off) ? sb[threadIdx.x - off] : 0;
    __syncthreads();
    sb[threadIdx.x] += add;
    __syncthreads();
  }
  int excl = sb[threadIdx.x] - s + boff[blockIdx.x];
#pragma unroll
  for (int j = 0; j < 4; j++) {
    int i = i0 + j;
    if (i < n) { row_ptr[i] = excl; cursor[i] = excl; excl += c[j]; }
  }
}

__global__ __launch_bounds__(256) void k_scatter(const int* __restrict__ srce,
                                                 const int* __restrict__ dste, int E, int n,
                                                 int* __restrict__ cursor,
                                                 int* __restrict__ srcs) {
  int t = blockIdx.x * 256 + threadIdx.x;
  if (t >= E + n) return;
  int s, d;
  if (t < E) { s = srce[t]; d = dste[t]; } else { s = d = t - E; }
  int pos = atomicAdd(&cursor[d], 1);
  srcs[pos] = s;
}

// -------------------- W1 transpose to bf16 (once) --------------------

// W1 [128][256] fp32 -> W1T [256][128] bf16.
__global__ __launch_bounds__(256) void k_w1t(const float* __restrict__ W,
                                             unsigned short* __restrict__ WT) {
  int t = blockIdx.x * 256 + threadIdx.x;  // 32768 total
  int k = t >> 8;        // 0..127
  int nn = t & 255;      // 0..255, consecutive lanes -> coalesced read
  WT[nn * 128 + k] = f2bf(W[k * 256 + nn]);
}

// -------------------- GEMM1: bf16 MFMA + fused alpha epilogue ------------

// X[M,128] fp32 @ W1T[256][128] bf16 -> h1 bf16 [M,256] + a_s1/a_d1 [M,8].
// Block: 64 rows, 256 thr (4 waves); wave w owns 64-col slab (= heads 2w,2w+1).
// 4x4 16x16x32 acc tiles/wave; K in two 64-chunks (B restaged per chunk).
__global__ __launch_bounds__(256) void gemm1_mfma(const float* __restrict__ X,
                                                  const unsigned short* __restrict__ WT,
                                                  const float* __restrict__ a_src,
                                                  const float* __restrict__ a_dst,
                                                  unsigned short* __restrict__ h1,
                                                  float* __restrict__ a_s1,
                                                  float* __restrict__ a_d1,
                                                  int M) {
  __shared__ unsigned short As[64 * 136];   // row stride 136 bf16 (272 B)
  __shared__ unsigned short Bs[256 * 72];   // row stride 72 bf16 (144 B)
  const int row0 = blockIdx.x * 64;
  const int tid = threadIdx.x;
  const int wv = tid >> 6, lane = tid & 63;
  const int quad = lane >> 4, l15 = lane & 15;
  const int colw = wv * 64;

  // stage A (full K), fp32 -> bf16 packed, b64 LDS writes
#pragma unroll
  for (int i = 0; i < 8; i++) {
    int j = tid + 256 * i;
    int r = j >> 5;
    int c4 = (j & 31) * 4;
    float4 v = make_float4(0.f, 0.f, 0.f, 0.f);
    if (row0 + r < M) v = *(const float4*)&X[(size_t)(row0 + r) * 128 + c4];
    uint2 p;
    p.x = (unsigned)f2bf(v.x) | ((unsigned)f2bf(v.y) << 16);
    p.y = (unsigned)f2bf(v.z) | ((unsigned)f2bf(v.w) << 16);
    *(uint2*)&As[r * 136 + c4] = p;
  }

  f32x4 acc[16];
#pragma unroll
  for (int i = 0; i < 16; i++) acc[i] = (f32x4)0.f;

  for (int kc = 0; kc < 128; kc += 64) {
    __syncthreads();
    // stage Bs[n][0..64] = WT[n][kc..kc+64]; pure b128 copies
#pragma unroll
    for (int i = 0; i < 8; i++) {
      int j = tid + 256 * i;          // 0..2047
      int nn = j >> 3;                // 0..255
      int kg = (j & 7) * 8;           // 0..56
      *(uint4*)&Bs[nn * 72 + kg] = *(const uint4*)&WT[nn * 128 + kc + kg];
    }
    __syncthreads();
#pragma unroll
    for (int ks = 0; ks < 64; ks += 32) {
      bf16x8 af[4], bfr[4];
#pragma unroll
      for (int mi = 0; mi < 4; mi++)
        af[mi] = *(const bf16x8*)&As[(mi * 16 + l15) * 136 + kc + ks + quad * 8];
#pragma unroll
      for (int ni = 0; ni < 4; ni++)
        bfr[ni] = *(const bf16x8*)&Bs[(colw + ni * 16 + l15) * 72 + ks + quad * 8];
#pragma unroll
      for (int mi = 0; mi < 4; mi++)
#pragma unroll
        for (int ni = 0; ni < 4; ni++)
          acc[mi * 4 + ni] = __builtin_amdgcn_mfma_f32_16x16x32_bf16(
              af[mi], bfr[ni], acc[mi * 4 + ni], 0, 0, 0);
    }
  }

  // epilogue: h1 store + fused alpha dots from fp32 accumulators.
  // D[m][n]: m = mi*16 + quad*4 + r, n = colw + ni*16 + l15.
  // a_src/a_dst flat index == global channel n (heads contiguous, 32 ch each).
  float as_[4], ad_[4];
#pragma unroll
  for (int ni = 0; ni < 4; ni++) {
    int nn = colw + ni * 16 + l15;
    as_[ni] = a_src[nn];
    ad_[ni] = a_dst[nn];
  }
  const int h0 = colw >> 5;  // first head of this wave's slab (= 2*wv)
#pragma unroll
  for (int mi = 0; mi < 4; mi++) {
#pragma unroll
    for (int r = 0; r < 4; r++) {
      int m = row0 + mi * 16 + quad * 4 + r;
      bool valid = (m < M);
      if (valid) {
#pragma unroll
        for (int ni = 0; ni < 4; ni++)
          h1[(size_t)m * 256 + colw + ni * 16 + l15] = f2bf(acc[mi * 4 + ni][r]);
      }
      // head h0: ni 0,1; head h0+1: ni 2,3
      float s0 = fmaf(acc[mi * 4 + 0][r], as_[0], acc[mi * 4 + 1][r] * as_[1]);
      float s1 = fmaf(acc[mi * 4 + 2][r], as_[2], acc[mi * 4 + 3][r] * as_[3]);
      float d0 = fmaf(acc[mi * 4 + 0][r], ad_[0], acc[mi * 4 + 1][r] * ad_[1]);
      float d1 = fmaf(acc[mi * 4 + 2][r], ad_[2], acc[mi * 4 + 3][r] * ad_[3]);
#pragma unroll
      for (int mk = 1; mk <= 8; mk <<= 1) {
        s0 += __shfl_xor(s0, mk);
        s1 += __shfl_xor(s1, mk);
        d0 += __shfl_xor(d0, mk);
        d1 += __shfl_xor(d1, mk);
      }
      if (l15 == 0 && valid) {
        a_s1[m * 8 + h0]     = s0;
        a_s1[m * 8 + h0 + 1] = s1;
        a_d1[m * 8 + h0]     = d0;
        a_d1[m * 8 + h0 + 1] = d1;
      }
    }
  }
}

// -------------------- GEMM2 + alpha epilogue (x2 in bf16) --------------------

__global__ __launch_bounds__(256) void gemm2(const unsigned short* __restrict__ Xb,
                                             const float* __restrict__ W,
                                             const float* __restrict__ a_src,
                                             const float* __restrict__ a_dst,
                                             float* __restrict__ h2,
                                             float* __restrict__ a_s2,
                                             float* __restrict__ a_d2, int M) {
  __shared__ float lx[64 * 132];  // padded stride 132
  int row0 = blockIdx.x * 64;
  int tc = threadIdx.x & 7;    // head; cols 4*tc..4*tc+3
  int tr = threadIdx.x >> 3;   // rows tr*2, tr*2+1
  float4 acc[2];
  acc[0] = make_float4(0.f, 0.f, 0.f, 0.f);
  acc[1] = make_float4(0.f, 0.f, 0.f, 0.f);
  for (int kk = 0; kk < 256; kk += 128) {
    __syncthreads();
#pragma unroll
    for (int i = 0; i < 8; i++) {
      int j = threadIdx.x + 256 * i;  // 4-elem group index, 2048 total
      int r = j >> 5;
      int c = (j & 31) * 4;
      float4 v = make_float4(0.f, 0.f, 0.f, 0.f);
      if (row0 + r < M) {
        uint2 q = *(const uint2*)&Xb[(size_t)(row0 + r) * 256 + kk + c];
        v = make_float4(bf_lo(q.x), bf_hi(q.x), bf_lo(q.y), bf_hi(q.y));
      }
      *(float4*)&lx[r * 132 + c] = v;
    }
    __syncthreads();
    for (int k = 0; k < 128; k++) {
      float4 w4 = *(const float4*)&W[(kk + k) * 32 + tc * 4];
#pragma unroll
      for (int i = 0; i < 2; i++) {
        float xv = lx[(tr * 2 + i) * 132 + k];
        acc[i].x = fmaf(xv, w4.x, acc[i].x);
        acc[i].y = fmaf(xv, w4.y, acc[i].y);
        acc[i].z = fmaf(xv, w4.z, acc[i].z);
        acc[i].w = fmaf(xv, w4.w, acc[i].w);
      }
    }
  }
  float4 asv = *(const float4*)&a_src[tc * 4];
  float4 adv = *(const float4*)&a_dst[tc * 4];
#pragma unroll
  for (int i = 0; i < 2; i++) {
    int r = row0 + tr * 2 + i;
    if (r < M) {
      float ps = acc[i].x * asv.x;
      ps = fmaf(acc[i].y, asv.y, ps);
      ps = fmaf(acc[i].z, asv.z, ps);
      ps = fmaf(acc[i].w, asv.w, ps);
      float pd = acc[i].x * adv.x;
      pd = fmaf(acc[i].y, adv.y, pd);
      pd = fmaf(acc[i].z, adv.z, pd);
      pd = fmaf(acc[i].w, adv.w, pd);
      *(float4*)&h2[(size_t)r * 32 + tc * 4] = acc[i];
      a_s2[r * 8 + tc] = ps;
      a_d2[r * 8 + tc] = pd;
    }
  }
}

// -------------------- segment softmax + aggregation --------------------

// Layer 1: F=256 bf16 in, bf16 out. Single-pass softmax, 16 gathers in
// flight, 2 independent accumulator chains, predicated batch tail.
__global__ __launch_bounds__(256) void gat_agg_l1(const unsigned short* __restrict__ h,
                                                  const float* __restrict__ asrc,
                                                  const float* __restrict__ adst,
                                                  const int* __restrict__ row_ptr,
                                                  const int* __restrict__ srcs,
                                                  const float* __restrict__ bias,
                                                  unsigned short* __restrict__ out, int n) {
  int wave = threadIdx.x >> 6;
  int lane = threadIdx.x & 63;
  int d = blockIdx.x * 4 + wave;
  if (d >= n) return;
  int begin = row_ptr[d];
  int end = row_ptr[d + 1];
  int hh = lane & 7;
  float ad = adst[d * 8 + hh];

  const int myhead = lane >> 3;
  float denom = 0.f;
  float4 acc0 = make_float4(0.f, 0.f, 0.f, 0.f);
  float4 acc1 = make_float4(0.f, 0.f, 0.f, 0.f);
#define ACCA(ff, qq)                                        \
    acc0.x = fmaf(ff, bf_lo(qq.x), acc0.x);                 \
    acc0.y = fmaf(ff, bf_hi(qq.x), acc0.y);                 \
    acc0.z = fmaf(ff, bf_lo(qq.y), acc0.z);                 \
    acc0.w = fmaf(ff, bf_hi(qq.y), acc0.w);
#define ACCB(ff, qq)                                        \
    acc1.x = fmaf(ff, bf_lo(qq.x), acc1.x);                 \
    acc1.y = fmaf(ff, bf_hi(qq.x), acc1.y);                 \
    acc1.z = fmaf(ff, bf_lo(qq.y), acc1.z);                 \
    acc1.w = fmaf(ff, bf_hi(qq.y), acc1.w);

  int e = begin;
  for (; e + 16 <= end; e += 16) {
    int s[16];
#pragma unroll
    for (int j = 0; j < 16; j++) s[j] = srcs[e + j];
    float w[16];
    if (lane < 8) {
#pragma unroll
      for (int j = 0; j < 16; j++) {
        w[j] = __expf(lrelu(asrc[s[j] * 8 + lane] + ad));
        denom += w[j];
      }
    } else {
#pragma unroll
      for (int j = 0; j < 16; j++) w[j] = 0.f;
    }
    uint2 q[16];
#pragma unroll
    for (int j = 0; j < 16; j++) q[j] = *(const uint2*)&h[(size_t)s[j] * 256 + lane * 4];
    float f[16];
#pragma unroll
    for (int j = 0; j < 16; j++) f[j] = __shfl(w[j], myhead);
#pragma unroll
    for (int j = 0; j < 16; j += 2) {
      ACCA(f[j], q[j])
      ACCB(f[j + 1], q[j + 1])
    }
  }
  // predicated tail: up to two 8-batches cover any remainder (end-e < 16)
  for (; e < end; e += 8) {
    int s[8];
    float w[8];
#pragma unroll
    for (int j = 0; j < 8; j++) {
      int ee = e + j;
      s[j] = srcs[ee < end ? ee : end - 1];
    }
    if (lane < 8) {
#pragma unroll
      for (int j = 0; j < 8; j++) {
        float v = __expf(lrelu(asrc[s[j] * 8 + lane] + ad));
        w[j] = (e + j < end) ? v : 0.f;
        denom += w[j];
      }
    } else {
#pragma unroll
      for (int j = 0; j < 8; j++) w[j] = 0.f;
    }
    uint2 q[8];
#pragma unroll
    for (int j = 0; j < 8; j++) q[j] = *(const uint2*)&h[(size_t)s[j] * 256 + lane * 4];
    float f[8];
#pragma unroll
    for (int j = 0; j < 8; j++) f[j] = __shfl(w[j], myhead);
#pragma unroll
    for (int j = 0; j < 8; j += 2) {
      ACCA(f[j], q[j])
      ACCB(f[j + 1], q[j + 1])
    }
  }
#undef ACCA
#undef ACCB
  float4 acc;
  acc.x = acc0.x + acc1.x;
  acc.y = acc0.y + acc1.y;
  acc.z = acc0.z + acc1.z;
  acc.w = acc0.w + acc1.w;
  float dn = __shfl(denom, myhead) + 1e-16f;
  float inv = 1.f / dn;
  int f = lane * 4;
  float4 bv = *(const float4*)&bias[f];
  float rx = lrelu(acc.x * inv + bv.x);
  float ry = lrelu(acc.y * inv + bv.y);
  float rz = lrelu(acc.z * inv + bv.z);
  float rw = lrelu(acc.w * inv + bv.w);
  uint2 p;
  p.x = (unsigned)f2bf(rx) | ((unsigned)f2bf(ry) << 16);
  p.y = (unsigned)f2bf(rz) | ((unsigned)f2bf(rw) << 16);
  *(uint2*)&out[(size_t)d * 256 + f] = p;
}

// Layer 2: C=4, F=32. 8 edges in parallel per wave, unrolled x2.
__global__ __launch_bounds__(256) void gat_agg_l2(const float* __restrict__ h,
                                                  const float* __restrict__ asrc,
                                                  const float* __restrict__ adst,
                                                  const int* __restrict__ row_ptr,
                                                  const int* __restrict__ srcs,
                                                  const float* __restrict__ bias,
                                                  float* __restrict__ out, int n) {
  int wave = threadIdx.x >> 6;
  int lane = threadIdx.x & 63;
  int d = blockIdx.x * 4 + wave;
  if (d >= n) return;
  int begin = row_ptr[d];
  int end = row_ptr[d + 1];
  int hh = lane & 7;
  int eg = lane >> 3;
  float ad = adst[d * 8 + hh];

  float denom = 0.f;
  float4 acc = make_float4(0.f, 0.f, 0.f, 0.f);
  int base = begin;
  for (; base + 16 <= end; base += 16) {
    int sA = srcs[base + eg];
    int sB = srcs[base + 8 + eg];
    float aA = asrc[sA * 8 + hh];
    float aB = asrc[sB * 8 + hh];
    const float4 hA = *(const float4*)&h[(size_t)sA * 32 + hh * 4];
    const float4 hB = *(const float4*)&h[(size_t)sB * 32 + hh * 4];
    float wA = __expf(lrelu(aA + ad));
    float wB = __expf(lrelu(aB + ad));
    denom += wA + wB;
    acc.x = fmaf(wA, hA.x, acc.x); acc.y = fmaf(wA, hA.y, acc.y);
    acc.z = fmaf(wA, hA.z, acc.z); acc.w = fmaf(wA, hA.w, acc.w);
    acc.x = fmaf(wB, hB.x, acc.x); acc.y = fmaf(wB, hB.y, acc.y);
    acc.z = fmaf(wB, hB.z, acc.z); acc.w = fmaf(wB, hB.w, acc.w);
  }
  for (; base < end; base += 8) {
    int e = base + eg;
    if (e < end) {
      int s = srcs[e];
      float w = __expf(lrelu(asrc[s * 8 + hh] + ad));
      denom += w;
      const float4 hv = *(const float4*)&h[(size_t)s * 32 + hh * 4];
      acc.x = fmaf(w, hv.x, acc.x);
      acc.y = fmaf(w, hv.y, acc.y);
      acc.z = fmaf(w, hv.z, acc.z);
      acc.w = fmaf(w, hv.w, acc.w);
    }
  }
#pragma unroll
  for (int mask = 8; mask <= 32; mask <<= 1) {
    denom += __shfl_xor(denom, mask);
    acc.x += __shfl_xor(acc.x, mask);
    acc.y += __shfl_xor(acc.y, mask);
    acc.z += __shfl_xor(acc.z, mask);
    acc.w += __shfl_xor(acc.w, mask);
  }
  if (lane < 8) {
    float inv = 1.f / (denom + 1e-16f);
    int f = lane * 4;
    float4 bv = *(const float4*)&bias[f];
    float4 r;
    r.x = acc.x * inv + bv.x;
    r.y = acc.y * inv + bv.y;
    r.z = acc.z * inv + bv.z;
    r.w = acc.w * inv + bv.w;
    *(float4*)&out[(size_t)d * 32 + f] = r;
  }
}

// -------------------- launcher --------------------

extern "C" void kernel_launch(void* const* d_in, const int* in_sizes, int n_in,
                              void* d_out, int out_size, void* d_ws, size_t ws_size,
                              hipStream_t stream) {
  const float* x   = (const float*)d_in[0];
  const int*   ei  = (const int*)d_in[1];
  const float* W1  = (const float*)d_in[2];
  const float* as1 = (const float*)d_in[3];
  const float* ad1 = (const float*)d_in[4];
  const float* b1  = (const float*)d_in[5];
  const float* W2  = (const float*)d_in[6];
  const float* as2 = (const float*)d_in[7];
  const float* ad2 = (const float*)d_in[8];
  const float* b2  = (const float*)d_in[9];
  float* out = (float*)d_out;

  const int E = in_sizes[1] / 2;
  const int n = in_sizes[0] / 128;
  const int* srce = ei;
  const int* dste = ei + E;

  char* ws = (char*)d_ws;
  size_t off = 0;
  auto alloc = [&](size_t bytes) -> void* {
    void* p = ws + off;
    off = (off + bytes + 255) & ~(size_t)255;
    return p;
  };
  int* cnt      = (int*)alloc((size_t)n * 4);
  int* row_ptr  = (int*)alloc((size_t)(n + 1) * 4);
  int* cursor   = (int*)alloc((size_t)n * 4);
  int* bsum     = (int*)alloc(256 * 4);
  int* boff     = (int*)alloc(256 * 4);
  int* srcs     = (int*)alloc((size_t)(E + n) * 4);
  unsigned short* h1  = (unsigned short*)alloc((size_t)n * 256 * 2);  // bf16
  unsigned short* w1t = (unsigned short*)alloc((size_t)256 * 128 * 2);
  float* a_s1   = (float*)alloc((size_t)n * 8 * 4);
  float* a_d1   = (float*)alloc((size_t)n * 8 * 4);
  unsigned short* x2 = (unsigned short*)alloc((size_t)n * 256 * 2);   // bf16
  float* h2     = (float*)alloc((size_t)n * 32 * 4);
  float* a_s2   = (float*)alloc((size_t)n * 8 * 4);
  float* a_d2   = (float*)alloc((size_t)n * 8 * 4);

  const int tot = E + n;
  hipMemsetAsync(cnt, 0, (size_t)n * 4, stream);
  k_w1t<<<128, 256, 0, stream>>>(W1, w1t);
  k_hist<<<(tot + 255) / 256, 256, 0, stream>>>(dste, E, n, cnt);
  const int nb = (n + 1023) / 1024;
  k_scan1<<<nb, 256, 0, stream>>>(cnt, n, bsum);
  k_scan2<<<1, 64, 0, stream>>>(bsum, nb, boff, row_ptr, n);
  k_scan3<<<nb, 256, 0, stream>>>(cnt, boff, n, row_ptr, cursor);
  k_scatter<<<(tot + 255) / 256, 256, 0, stream>>>(srce, dste, E, n, cursor, srcs);

  gemm1_mfma<<<(n + 63) / 64, 256, 0, stream>>>(x, w1t, as1, ad1, h1, a_s1, a_d1, n);
  gat_agg_l1<<<(n + 3) / 4, 256, 0, stream>>>(h1, a_s1, a_d1, row_ptr, srcs, b1, x2, n);

  gemm2<<<(n + 63) / 64, 256, 0, stream>>>(x2, W2, as2, ad2, h2, a_s2, a_d2, n);
  gat_agg_l2<<<(n + 3) / 4, 256, 0, stream>>>(h2, a_s2, a_d2, row_ptr, srcs, b2, out, n);
}